// Round 4
// baseline (70.748 us; speedup 1.0000x reference)
//
#include <hip/hip_runtime.h>

#define NCLS  19
#define NBINS 15
#define HW    (512 * 512)        // 262144
#define NPIX  (8 * HW)           // 2097152
#define QUADS (NPIX / 4)         // 524288

typedef float  f32x4 __attribute__((ext_vector_type(4)));  // native vec for NT ld/st

// exp(x) for x in ~[-7, 7]; rel err ~7e-12 (degree-9 exp2 Taylor).
// Well below f32 ulp (6e-8) -> bin decisions match an f64 reference.
__device__ __forceinline__ double dexp_fast(double x) {
    const double LOG2E = 1.4426950408889634074;
    double t = x * LOG2E;
    double n = rint(t);                 // v_rndne_f64
    double r = t - n;                   // exact, r in [-0.5, 0.5]
    double p;
    p =                  1.0178086009239699e-07;      // ln2^9/9!
    p = __builtin_fma(p, r, 1.3215486790144309e-06);  // ln2^8/8!
    p = __builtin_fma(p, r, 1.5252733804059840e-05);  // ln2^7/7!
    p = __builtin_fma(p, r, 1.5403530393381609e-04);  // ln2^6/6!
    p = __builtin_fma(p, r, 1.3333558146428443e-03);  // ln2^5/5!
    p = __builtin_fma(p, r, 9.6181291076284772e-03);  // ln2^4/4!
    p = __builtin_fma(p, r, 5.5504108664821580e-02);  // ln2^3/3!
    p = __builtin_fma(p, r, 2.4022650695910071e-01);  // ln2^2/2!
    p = __builtin_fma(p, r, 6.9314718055994531e-01);  // ln2
    p = __builtin_fma(p, r, 1.0);
    int ni = (int)n;
    long long bits = ((long long)(ni + 1023)) << 52;
    return p * __longlong_as_double(bits);
}

__global__ void __launch_bounds__(256)
histcal_kernel(const float* __restrict__ logits,
               const float* __restrict__ val_freqs,
               float* __restrict__ out)
{
    __shared__ float svf[NCLS * NBINS];
    for (int t = threadIdx.x; t < NCLS * NBINS; t += 256)
        svf[t] = val_freqs[t];
    __syncthreads();

    unsigned q   = blockIdx.x * 256u + threadIdx.x;   // quad index
    unsigned b   = q >> 16;                           // / (HW/4)
    unsigned hwq = q & 65535u;
    size_t base = (size_t)b * ((size_t)NCLS * HW) + (size_t)hwq * 4;
    const float* lp = logits + base;
    float*       op = out + base;

    // Phase 1: 19 independent float4 plane loads (16B/lane, all in flight).
    f32x4 x[NCLS];
    #pragma unroll
    for (int c = 0; c < NCLS; ++c)
        x[c] = *(const f32x4*)(lp + (size_t)c * HW);

    // Phase 2: f64 exps + per-pixel sums (shift-free softmax; |logit| < ~7).
    double e[NCLS][4];
    double s0 = 0.0, s1 = 0.0, s2 = 0.0, s3 = 0.0;
    #pragma unroll
    for (int c = 0; c < NCLS; ++c) {
        e[c][0] = dexp_fast((double)x[c][0]); s0 += e[c][0];
        e[c][1] = dexp_fast((double)x[c][1]); s1 += e[c][1];
        e[c][2] = dexp_fast((double)x[c][2]); s2 += e[c][2];
        e[c][3] = dexp_fast((double)x[c][3]); s3 += e[c][3];
    }
    double r0 = 15.0 / s0, r1 = 15.0 / s1, r2 = 15.0 / s2, r3 = 15.0 / s3;

    // Phase 3: bin (f64-exact), LDS gather, class-sums.
    f32x4 cal[NCLS];
    float t0 = 0.f, t1 = 0.f, t2 = 0.f, t3 = 0.f;
    #pragma unroll
    for (int c = 0; c < NCLS; ++c) {
        int b0 = (int)(e[c][0] * r0); b0 = b0 > NBINS - 1 ? NBINS - 1 : b0;
        int b1 = (int)(e[c][1] * r1); b1 = b1 > NBINS - 1 ? NBINS - 1 : b1;
        int b2 = (int)(e[c][2] * r2); b2 = b2 > NBINS - 1 ? NBINS - 1 : b2;
        int b3 = (int)(e[c][3] * r3); b3 = b3 > NBINS - 1 ? NBINS - 1 : b3;
        float v0 = svf[c * NBINS + b0];
        float v1 = svf[c * NBINS + b1];
        float v2 = svf[c * NBINS + b2];
        float v3 = svf[c * NBINS + b3];
        cal[c][0] = v0; t0 += v0;
        cal[c][1] = v1; t1 += v1;
        cal[c][2] = v2; t2 += v2;
        cal[c][3] = v3; t3 += v3;
    }
    if (t0 == 0.f) t0 = 1.f;
    if (t1 == 0.f) t1 = 1.f;
    if (t2 == 0.f) t2 = 1.f;
    if (t3 == 0.f) t3 = 1.f;
    float i0 = 1.f / t0, i1 = 1.f / t1, i2 = 1.f / t2, i3 = 1.f / t3;

    // Phase 4: streaming f32x4 write-out.
    #pragma unroll
    for (int c = 0; c < NCLS; ++c) {
        f32x4 r;
        r[0] = cal[c][0] * i0;
        r[1] = cal[c][1] * i1;
        r[2] = cal[c][2] * i2;
        r[3] = cal[c][3] * i3;
        __builtin_nontemporal_store(r, (f32x4*)(op + (size_t)c * HW));
    }
}

extern "C" void kernel_launch(void* const* d_in, const int* in_sizes, int n_in,
                              void* d_out, int out_size, void* d_ws, size_t ws_size,
                              hipStream_t stream) {
    const float* logits    = (const float*)d_in[0];   // [8,19,512,512] f32
    const float* val_freqs = (const float*)d_in[1];   // [19,15] f32
    float* out = (float*)d_out;                       // [8,19,512,512] f32
    histcal_kernel<<<dim3(QUADS / 256), dim3(256), 0, stream>>>(logits, val_freqs, out);
}

// Round 5
// 58.571 us; speedup vs baseline: 1.2079x; 1.2079x over previous
//
#include <hip/hip_runtime.h>

#define NCLS  19
#define NBINS 15
#define HW    (512 * 512)        // 262144
#define NPIX  (8 * HW)           // 2097152

// exp(x) for x in ~[-7, 7]; rel err ~7e-12 (degree-9 exp2 Taylor).
// Bin decisions need ~1e-10 rel accuracy vs the f64 numpy reference -> ok.
__device__ __forceinline__ double dexp_fast(double x) {
    const double LOG2E = 1.4426950408889634074;
    double t = x * LOG2E;
    double n = rint(t);                 // v_rndne_f64
    double r = t - n;                   // exact, r in [-0.5, 0.5]
    double p;
    p =                  1.0178086009239699e-07;      // ln2^9/9!
    p = __builtin_fma(p, r, 1.3215486790144309e-06);  // ln2^8/8!
    p = __builtin_fma(p, r, 1.5252733804059840e-05);  // ln2^7/7!
    p = __builtin_fma(p, r, 1.5403530393381609e-04);  // ln2^6/6!
    p = __builtin_fma(p, r, 1.3333558146428443e-03);  // ln2^5/5!
    p = __builtin_fma(p, r, 9.6181291076284772e-03);  // ln2^4/4!
    p = __builtin_fma(p, r, 5.5504108664821580e-02);  // ln2^3/3!
    p = __builtin_fma(p, r, 2.4022650695910071e-01);  // ln2^2/2!
    p = __builtin_fma(p, r, 6.9314718055994531e-01);  // ln2
    p = __builtin_fma(p, r, 1.0);
    int ni = (int)n;
    long long bits = ((long long)(ni + 1023)) << 52;
    return p * __longlong_as_double(bits);
}

__global__ void __launch_bounds__(256)
histcal_kernel(const float* __restrict__ logits,
               const float* __restrict__ val_freqs,
               float* __restrict__ out)
{
    __shared__ float svf[NCLS * NBINS];
    for (int t = threadIdx.x; t < NCLS * NBINS; t += 256)
        svf[t] = val_freqs[t];
    __syncthreads();

    unsigned i  = blockIdx.x * 256u + threadIdx.x;
    unsigned b  = i >> 18;            // / HW
    unsigned hw = i & (HW - 1);
    size_t base = (size_t)b * ((size_t)NCLS * HW) + hw;
    const float* lp = logits + base;
    float*       op = out + base;

    // Pass 1: one exp per element, e[] PINNED in VGPRs (38 regs) so the
    // compiler can neither rematerialize the exp nor reload x from global.
    double e[NCLS];
    double s = 0.0;
    #pragma unroll
    for (int c = 0; c < NCLS; ++c) {
        float x = lp[(size_t)c * HW];       // coalesced plane load
        double ev = dexp_fast((double)x);
        asm volatile("" : "+v"(ev));        // pin: forbid remat/reload
        e[c] = ev;
        s += ev;
    }
    double sc = 15.0 / s;

    // Pass 2: bin in f64, pack 4-bit bins into 3 u32s, accumulate class-sum.
    unsigned pb0 = 0, pb1 = 0, pb2 = 0;
    float t = 0.f;
    #pragma unroll
    for (int c = 0; c < NCLS; ++c) {
        int bi = (int)(e[c] * sc);          // >=0, trunc == floor
        bi = bi > NBINS - 1 ? NBINS - 1 : bi;
        t += svf[c * NBINS + bi];
        if (c < 8)       pb0 |= (unsigned)bi << (4 * c);
        else if (c < 16) pb1 |= (unsigned)bi << (4 * (c - 8));
        else             pb2 |= (unsigned)bi << (4 * (c - 16));
    }
    if (t == 0.f) t = 1.f;
    float inv = 1.f / t;

    // Pass 3: unpack bins, re-gather, normalize, streaming store.
    #pragma unroll
    for (int c = 0; c < NCLS; ++c) {
        unsigned bi = (c < 8) ? (pb0 >> (4 * c)) & 15u
                    : (c < 16) ? (pb1 >> (4 * (c - 8))) & 15u
                               : (pb2 >> (4 * (c - 16))) & 15u;
        float v = svf[c * NBINS + bi];
        __builtin_nontemporal_store(v * inv, op + (size_t)c * HW);
    }
}

extern "C" void kernel_launch(void* const* d_in, const int* in_sizes, int n_in,
                              void* d_out, int out_size, void* d_ws, size_t ws_size,
                              hipStream_t stream) {
    const float* logits    = (const float*)d_in[0];   // [8,19,512,512] f32
    const float* val_freqs = (const float*)d_in[1];   // [19,15] f32
    float* out = (float*)d_out;                       // [8,19,512,512] f32
    histcal_kernel<<<dim3(NPIX / 256), dim3(256), 0, stream>>>(logits, val_freqs, out);
}

// Round 6
// 56.232 us; speedup vs baseline: 1.2581x; 1.0416x over previous
//
#include <hip/hip_runtime.h>

#define NCLS  19
#define NBINS 15
#define HW    (512 * 512)        // 262144
#define NPIX  (8 * HW)           // 2097152
#define PAIRS (NPIX / 2)         // 1048576

typedef float f32x2 __attribute__((ext_vector_type(2)));

// exp(x) for x in ~[-7, 7]; rel err ~7e-12 (degree-9 exp2 Taylor).
// Bin decisions need ~1e-10 rel accuracy vs the f64 numpy reference -> ok.
__device__ __forceinline__ double dexp_fast(double x) {
    const double LOG2E = 1.4426950408889634074;
    double t = x * LOG2E;
    double n = rint(t);                 // v_rndne_f64
    double r = t - n;                   // exact, r in [-0.5, 0.5]
    double p;
    p =                  1.0178086009239699e-07;      // ln2^9/9!
    p = __builtin_fma(p, r, 1.3215486790144309e-06);  // ln2^8/8!
    p = __builtin_fma(p, r, 1.5252733804059840e-05);  // ln2^7/7!
    p = __builtin_fma(p, r, 1.5403530393381609e-04);  // ln2^6/6!
    p = __builtin_fma(p, r, 1.3333558146428443e-03);  // ln2^5/5!
    p = __builtin_fma(p, r, 9.6181291076284772e-03);  // ln2^4/4!
    p = __builtin_fma(p, r, 5.5504108664821580e-02);  // ln2^3/3!
    p = __builtin_fma(p, r, 2.4022650695910071e-01);  // ln2^2/2!
    p = __builtin_fma(p, r, 6.9314718055994531e-01);  // ln2
    p = __builtin_fma(p, r, 1.0);
    int ni = (int)n;
    long long bits = ((long long)(ni + 1023)) << 52;
    return p * __longlong_as_double(bits);
}

__global__ void __launch_bounds__(256)
histcal_kernel(const float* __restrict__ logits,
               const float* __restrict__ val_freqs,
               float* __restrict__ out)
{
    __shared__ float svf[NCLS * NBINS];
    for (int t = threadIdx.x; t < NCLS * NBINS; t += 256)
        svf[t] = val_freqs[t];
    __syncthreads();

    unsigned q   = blockIdx.x * 256u + threadIdx.x;   // pixel-pair index
    unsigned b   = q >> 17;                           // / (HW/2)
    unsigned hwp = q & ((HW / 2) - 1);
    size_t base = (size_t)b * ((size_t)NCLS * HW) + (size_t)hwp * 2;
    const float* lp = logits + base;
    float*       op = out + base;

    // Pass 1: fused load + exp + sum for both pixels (R2 structure x2).
    double e[NCLS][2];
    double s0 = 0.0, s1 = 0.0;
    #pragma unroll
    for (int c = 0; c < NCLS; ++c) {
        f32x2 x = *(const f32x2*)(lp + (size_t)c * HW);   // 8B coalesced
        e[c][0] = dexp_fast((double)x[0]); s0 += e[c][0];
        e[c][1] = dexp_fast((double)x[1]); s1 += e[c][1];
    }
    double r0 = 15.0 / s0, r1 = 15.0 / s1;

    // Pass 2: bin (f64-exact), LDS gather, class-sums.
    float cal[NCLS][2];
    float t0 = 0.f, t1 = 0.f;
    #pragma unroll
    for (int c = 0; c < NCLS; ++c) {
        int b0 = (int)(e[c][0] * r0); b0 = b0 > NBINS - 1 ? NBINS - 1 : b0;
        int b1 = (int)(e[c][1] * r1); b1 = b1 > NBINS - 1 ? NBINS - 1 : b1;
        float v0 = svf[c * NBINS + b0];
        float v1 = svf[c * NBINS + b1];
        cal[c][0] = v0; t0 += v0;
        cal[c][1] = v1; t1 += v1;
    }
    if (t0 == 0.f) t0 = 1.f;
    if (t1 == 0.f) t1 = 1.f;
    float i0 = 1.f / t0, i1 = 1.f / t1;

    // Pass 3: streaming 8B write-out.
    #pragma unroll
    for (int c = 0; c < NCLS; ++c) {
        f32x2 r;
        r[0] = cal[c][0] * i0;
        r[1] = cal[c][1] * i1;
        __builtin_nontemporal_store(r, (f32x2*)(op + (size_t)c * HW));
    }
}

extern "C" void kernel_launch(void* const* d_in, const int* in_sizes, int n_in,
                              void* d_out, int out_size, void* d_ws, size_t ws_size,
                              hipStream_t stream) {
    const float* logits    = (const float*)d_in[0];   // [8,19,512,512] f32
    const float* val_freqs = (const float*)d_in[1];   // [19,15] f32
    float* out = (float*)d_out;                       // [8,19,512,512] f32
    histcal_kernel<<<dim3(PAIRS / 256), dim3(256), 0, stream>>>(logits, val_freqs, out);
}

// Round 7
// 54.071 us; speedup vs baseline: 1.3084x; 1.0400x over previous
//
#include <hip/hip_runtime.h>

#define NCLS  19
#define NBINS 15
#define HW    (512 * 512)        // 262144
#define NPIX  (8 * HW)           // 2097152

// exp(x) for x in ~[-7, 7]; rel err ~7e-12 (degree-9 exp2 Taylor).
// Bin decisions need ~1e-10 rel accuracy vs the f64 numpy reference -> ok.
__device__ __forceinline__ double dexp_fast(double x) {
    const double LOG2E = 1.4426950408889634074;
    double t = x * LOG2E;
    double n = rint(t);                 // v_rndne_f64
    double r = t - n;                   // exact, r in [-0.5, 0.5]
    double p;
    p =                  1.0178086009239699e-07;      // ln2^9/9!
    p = __builtin_fma(p, r, 1.3215486790144309e-06);  // ln2^8/8!
    p = __builtin_fma(p, r, 1.5252733804059840e-05);  // ln2^7/7!
    p = __builtin_fma(p, r, 1.5403530393381609e-04);  // ln2^6/6!
    p = __builtin_fma(p, r, 1.3333558146428443e-03);  // ln2^5/5!
    p = __builtin_fma(p, r, 9.6181291076284772e-03);  // ln2^4/4!
    p = __builtin_fma(p, r, 5.5504108664821580e-02);  // ln2^3/3!
    p = __builtin_fma(p, r, 2.4022650695910071e-01);  // ln2^2/2!
    p = __builtin_fma(p, r, 6.9314718055994531e-01);  // ln2
    p = __builtin_fma(p, r, 1.0);
    int ni = (int)n;
    long long bits = ((long long)(ni + 1023)) << 52;
    return p * __longlong_as_double(bits);
}

__global__ void __launch_bounds__(256)
histcal_kernel(const float* __restrict__ logits,
               const float* __restrict__ val_freqs,
               float* __restrict__ out)
{
    __shared__ float svf[NCLS * NBINS];
    for (int t = threadIdx.x; t < NCLS * NBINS; t += 256)
        svf[t] = val_freqs[t];
    __syncthreads();

    unsigned i  = blockIdx.x * 256u + threadIdx.x;
    unsigned b  = i >> 18;            // / HW
    unsigned hw = i & (HW - 1);
    size_t base = (size_t)b * ((size_t)NCLS * HW) + hw;
    const float* lp = logits + base;
    float*       op = out + base;

    // Phase 1: issue ALL 19 plane loads back-to-back (max MLP), then pin.
    // The pin forces every load to be issued before any compute consumes one,
    // so one vmcnt-wait amortizes a single HBM latency over 19 requests.
    float x[NCLS];
    #pragma unroll
    for (int c = 0; c < NCLS; ++c)
        x[c] = lp[(size_t)c * HW];
    #pragma unroll
    for (int c = 0; c < NCLS; ++c)
        asm volatile("" : "+v"(x[c]));

    // Phase 2: exp + sum (compiler free to recompute exps later from x[]).
    double s = 0.0;
    #pragma unroll
    for (int c = 0; c < NCLS; ++c)
        s += dexp_fast((double)x[c]);
    double sc = 15.0 / s;

    // Phase 3: bin (f64-exact), LDS gather, class-sum.
    float cal[NCLS];
    float t = 0.f;
    #pragma unroll
    for (int c = 0; c < NCLS; ++c) {
        int bi = (int)(dexp_fast((double)x[c]) * sc);   // >=0, trunc == floor
        bi = bi > NBINS - 1 ? NBINS - 1 : bi;
        float v = svf[c * NBINS + bi];
        cal[c] = v;
        t += v;
    }
    if (t == 0.f) t = 1.f;
    float inv = 1.f / t;

    // Phase 4: streaming write-out.
    #pragma unroll
    for (int c = 0; c < NCLS; ++c)
        __builtin_nontemporal_store(cal[c] * inv, op + (size_t)c * HW);
}

extern "C" void kernel_launch(void* const* d_in, const int* in_sizes, int n_in,
                              void* d_out, int out_size, void* d_ws, size_t ws_size,
                              hipStream_t stream) {
    const float* logits    = (const float*)d_in[0];   // [8,19,512,512] f32
    const float* val_freqs = (const float*)d_in[1];   // [19,15] f32
    float* out = (float*)d_out;                       // [8,19,512,512] f32
    histcal_kernel<<<dim3(NPIX / 256), dim3(256), 0, stream>>>(logits, val_freqs, out);
}